// Round 11
// baseline (186.068 us; speedup 1.0000x reference)
//
#include <hip/hip_runtime.h>
#include <hip/hip_bf16.h>

#define NN 512
#define NH 64
#define MAXD 96            // list capacity (deg mean 32, sigma 5.5 -> +11 sigma)
#define ZBYTE (511 * 128)  // sentinel -> byte offset of row 511 (deg=0 always zeroes it)
#define REP_BG 8           // DIAGNOSTIC: internal repeat of build_gemms body
#define REP_HK 4           // DIAGNOSTIC: internal repeat of hidk k-loop

typedef _Float16 h4 __attribute__((ext_vector_type(4)));

// ---------------- ws layout (bytes) ----------------
// nbr  : NN*MAXD*4 = 196608 @ 0        entries = r*128 (byte row offset), sentinel ZBYTE
// g16  : NN*NH*2   = 65536  @ 196608   fp16 z@W1 tile (unscaled)
// pcnt : NN*NN*1   = 262144 @ 262144   u8 pcnt[i][c] = #{r in nbr(c): r < i}
// hidt : NN*NN*4   = 1048576@ 524288   f32 hid[i][k], valid k < i
// total = 1572864

__global__ __launch_bounds__(512) void build_gemms(const float* __restrict__ adj,
                                                   const float* __restrict__ z,
                                                   const float* __restrict__ W1,
                                                   unsigned* __restrict__ nbr,
                                                   unsigned char* __restrict__ pcnt,
                                                   _Float16* __restrict__ g16,
                                                   float* __restrict__ out) {
    __shared__ float As[32][34];
    __shared__ float Bs[32][34];
    __shared__ int wcnt[8];
    const int b = (int)blockIdx.x;
    const int tid = (int)threadIdx.x;
    const int lane = tid & 63, w = tid >> 6;

    for (int rep = 0; rep < REP_BG; ++rep) {   // DIAGNOSTIC repeat (idempotent)
        {   // build lists + pcnt for column c = b (adj symmetric)
            const int c = b;
            bool f = (adj[c * NN + tid] != 0.0f);
            unsigned long long m = __ballot(f);
            int before = __popcll(m & ((1ull << lane) - 1ull));
            if (lane == 0) wcnt[w] = __popcll(m);
            __syncthreads();
            int pre = 0, total = 0;
            #pragma unroll
            for (int j = 0; j < 8; ++j) {
                int x = wcnt[j];
                pre += (j < w) ? x : 0;
                total += x;
            }
            pcnt[tid * NN + c] = (unsigned char)(pre + before);  // pcnt[i][c]
            unsigned* row = nbr + c * MAXD;
            int pos = pre + before;
            if (f && pos < MAXD) row[pos] = (unsigned)(tid << 7);
            int m2 = total < MAXD ? total : MAXD;
            for (int j = m2 + tid; j < MAXD; j += 512) row[j] = ZBYTE;
            __syncthreads();
        }

        const int tx = tid & 15, py = tid >> 4;   // 16 x 32 thread layout
        if (b < 256) {
            const int bi = b >> 4, bj = b & 15;
            float acc0 = 0.f, acc1 = 0.f;
            for (int kk = 0; kk < 256; kk += 32) {
                #pragma unroll
                for (int l = 0; l < 2; ++l) {
                    int id = tid + (l << 9);
                    int m = id >> 5, k = id & 31;
                    As[k][m] = z[(bi * 32 + m) * 256 + kk + k];
                    Bs[k][m] = z[(bj * 32 + m) * 256 + kk + k];
                }
                __syncthreads();
                #pragma unroll
                for (int k = 0; k < 32; ++k) {
                    float a = As[k][py];
                    float2 bb = *(const float2*)&Bs[k][tx * 2];
                    acc0 = fmaf(a, bb.x, acc0);
                    acc1 = fmaf(a, bb.y, acc1);
                }
                __syncthreads();
            }
            *(float2*)&out[(bi * 32 + py) * NN + bj * 32 + tx * 2] = make_float2(acc0, acc1);
        } else if (b < 272) {
            const int bi = b - 256;
            float (*As2)[34] = As;
            float (*Bs2)[68] = (float(*)[68])&Bs[0][0];
            float a0 = 0.f, a1 = 0.f, a2 = 0.f, a3 = 0.f;
            for (int kk = 0; kk < 256; kk += 16) {
                {
                    int m = tid >> 4, k = tid & 15;
                    As2[k][m] = z[(bi * 32 + m) * 256 + kk + k];
                }
                #pragma unroll
                for (int l = 0; l < 2; ++l) {
                    int id = tid + (l << 9);
                    int k = id >> 6, n2 = id & 63;
                    Bs2[k][n2] = W1[(kk + k) * 64 + n2];
                }
                __syncthreads();
                #pragma unroll
                for (int k = 0; k < 16; ++k) {
                    float a = As2[k][py];
                    float4 bb = *(const float4*)&Bs2[k][tx * 4];
                    a0 = fmaf(a, bb.x, a0);
                    a1 = fmaf(a, bb.y, a1);
                    a2 = fmaf(a, bb.z, a2);
                    a3 = fmaf(a, bb.w, a3);
                }
                __syncthreads();
            }
            h4 v = {(_Float16)a0, (_Float16)a1, (_Float16)a2, (_Float16)a3};
            *(h4*)&g16[(bi * 32 + py) * NH + tx * 4] = v;
        }
        __syncthreads();
    }
}

// K2: visit-balanced hid (R10 structure). DIAGNOSTIC: k-loop repeated REP_HK x.
__global__ __launch_bounds__(1024, 8) void hidk(const unsigned* __restrict__ nbr,
                                                const unsigned char* __restrict__ pcnt,
                                                const _Float16* __restrict__ g16,
                                                const float* __restrict__ W2,
                                                float* __restrict__ hidt) {
    __shared__ _Float16 g2[NN * NH];   // 64 KB deg-scaled tile
    __shared__ float degl[NN];
    __shared__ unsigned char pcl[NN];
    const int i = 511 - (int)blockIdx.y;   // big i first
    const int c = (int)blockIdx.x;
    const int kc0 = (c * i) / 3, kc1 = ((c + 1) * i) / 3;
    if (kc0 >= kc1) return;
    const int tid = threadIdx.x, lane = tid & 63, w = tid >> 6;

    if (tid < NN) {
        int pc = (int)pcnt[i * NN + tid];            // coalesced 512B row
        pcl[tid] = (unsigned char)pc;
        degl[tid] = (tid < i) ? rsqrtf((float)(pc > 0 ? pc : 1)) : 0.0f;
    }
    __syncthreads();
    {
        const uint4* s = (const uint4*)g16;
        uint4* d = (uint4*)g2;
        #pragma unroll
        for (int u = 0; u < 4; ++u) {
            int t = tid + (u << 10);
            int l = t >> 3;
            uint4 raw = s[t];
            _Float16 dh = (_Float16)degl[l];
            h4 dv = {dh, dh, dh, dh};
            h4 a0 = ((h4*)&raw)[0] * dv;
            h4 a1 = ((h4*)&raw)[1] * dv;
            uint4 o;
            ((h4*)&o)[0] = a0; ((h4*)&o)[1] = a1;
            d[t] = o;
        }
    }
    __syncthreads();

    const int q = lane >> 4;                 // quarter 0..3
    const int lofs = (lane & 15) << 3;       // byte offset within 128B row
    const float4 w2v = *(const float4*)&W2[(lane & 15) << 2];
    const char* g2b = (const char*)g2;

    for (int rep = 0; rep < REP_HK; ++rep) {   // DIAGNOSTIC repeat (idempotent)
        for (int k0 = kc0 + (w << 2); k0 < kc1; k0 += 64) {
            const int kq = k0 + q;
            const int kqc = kq < 511 ? kq : 511;
            int pk = (kq < kc1) ? (int)pcl[kqc] : 0;
            int mx = max(pk, __shfl_xor(pk, 16, 64));
            mx = max(mx, __shfl_xor(mx, 32, 64));
            const int nbu = __builtin_amdgcn_readfirstlane((mx + 3) >> 2);
            const uint4* l4 = (const uint4*)(nbr + kqc * MAXD);
            h4 acc0 = {}, acc1 = {};
            uint4 e0 = l4[0], e1 = l4[1];        // 2-deep rolling prefetch
            for (int g = 0; g < nbu; ++g) {
                uint4 en = l4[g + 2];            // harmless in-row over-read
                acc0 += *(const h4*)(g2b + (e0.x + lofs));
                acc1 += *(const h4*)(g2b + (e0.y + lofs));
                acc0 += *(const h4*)(g2b + (e0.z + lofs));
                acc1 += *(const h4*)(g2b + (e0.w + lofs));
                e0 = e1; e1 = en;
            }
            h4 acc = acc0 + acc1;
            const float dk = degl[kqc];
            float val = fmaxf(dk * (float)acc[0], 0.f) * w2v.x
                      + fmaxf(dk * (float)acc[1], 0.f) * w2v.y
                      + fmaxf(dk * (float)acc[2], 0.f) * w2v.z
                      + fmaxf(dk * (float)acc[3], 0.f) * w2v.w;
            #pragma unroll
            for (int mm = 1; mm <= 8; mm <<= 1) val += __shfl_xor(val, mm, 64);
            if ((lane & 15) == 0 && kq < kc1) hidt[i * NN + kq] = val;
        }
    }
}

// K3: supplement scatter (unchanged from R10).
__global__ __launch_bounds__(512) void supp(const unsigned* __restrict__ nbr,
                                            const unsigned char* __restrict__ pcnt,
                                            const float* __restrict__ hidt,
                                            float* __restrict__ out) {
    __shared__ float phl[NN];
    const int i = 511 - (int)blockIdx.x;
    if (i < 1) return;
    const int tid = threadIdx.x;
    const int pc = (int)pcnt[i * NN + tid];          // coalesced row
    const float d = (tid < i) ? rsqrtf((float)(pc > 0 ? pc : 1)) : 0.0f;
    phl[tid] = (tid < i) ? d * hidt[i * NN + tid] : 0.0f;
    __syncthreads();
    if (tid < i) {
        const uint4* l4 = (const uint4*)(nbr + tid * MAXD);
        const int nb = (pc + 3) >> 2;
        float s = 0.f;
        for (int g = 0; g < nb; ++g) {
            uint4 qv = l4[g];   // over-read entries land on phl[r>=i] == 0
            s += phl[qv.x >> 7] + phl[qv.y >> 7] + phl[qv.z >> 7] + phl[qv.w >> 7];
        }
        s *= 0.5f * d;
        out[i * NN + tid] += s;
        out[tid * NN + i] += s;
    }
}

extern "C" void kernel_launch(void* const* d_in, const int* in_sizes, int n_in,
                              void* d_out, int out_size, void* d_ws, size_t ws_size,
                              hipStream_t stream) {
    const float* z   = (const float*)d_in[0];
    const float* adj = (const float*)d_in[1];
    const float* W1  = (const float*)d_in[2];
    const float* W2  = (const float*)d_in[3];
    float* out = (float*)d_out;

    char* wsp = (char*)d_ws;
    unsigned*       nbr  = (unsigned*)      (wsp + 0);
    _Float16*       g16  = (_Float16*)      (wsp + 196608);
    unsigned char*  pcnt = (unsigned char*) (wsp + 262144);
    float*          hidt = (float*)         (wsp + 524288);

    build_gemms<<<NN, 512, 0, stream>>>(adj, z, W1, nbr, pcnt, g16, out);
    hidk<<<dim3(3, NN), 1024, 0, stream>>>(nbr, pcnt, g16, W2, hidt);
    supp<<<NN, 512, 0, stream>>>(nbr, pcnt, hidt, out);
}

// Round 12
// 63.080 us; speedup vs baseline: 2.9497x; 2.9497x over previous
//
#include <hip/hip_runtime.h>
#include <hip/hip_bf16.h>

#define NN 512
#define NH 64
#define MAXD 96            // list capacity (deg mean 32, sigma 5.5 -> +11 sigma)
#define ZBYTE (511 * 128)  // sentinel -> byte offset of row 511 (deg=0 always zeroes it)

typedef _Float16 h4 __attribute__((ext_vector_type(4)));

// ---------------- ws layout (bytes) ----------------
// nbr   : NN*MAXD*4 = 196608 @ 0       entries = r*128 (byte row offset), sentinel ZBYTE
// g16   : NN*NH*2   = 65536  @ 196608  fp16 z@W1 tile (unscaled)
// pcntC : NN*NN*1   = 262144 @ 262144  u8 pcntC[c][t] = #{r in nbr(c): r < t}
//                                      (per-block coalesced row write -> no line contention)
// hidt  : NN*NN*4   = 1048576@ 524288  f32 hid[i][k], valid k < i
// total = 1572864

// K1: 512 blocks x 512 thr. Block b builds the neighbor list + prefix-count
// row for column c = b (adj symmetric). Blocks 0..255 also compute a 32x32
// tile of out = z@z^T; blocks 256..271 a 32-row slab of g16 = fp16(z@W1).
__global__ __launch_bounds__(512) void build_gemms(const float* __restrict__ adj,
                                                   const float* __restrict__ z,
                                                   const float* __restrict__ W1,
                                                   unsigned* __restrict__ nbr,
                                                   unsigned char* __restrict__ pcntC,
                                                   _Float16* __restrict__ g16,
                                                   float* __restrict__ out) {
    __shared__ float As[32][34];
    __shared__ float Bs[32][34];
    __shared__ int wcnt[8];
    const int b = (int)blockIdx.x;
    const int tid = (int)threadIdx.x;
    const int lane = tid & 63, w = tid >> 6;

    {   // build lists + own pcntC row for column c = b
        const int c = b;
        bool f = (adj[c * NN + tid] != 0.0f);
        unsigned long long m = __ballot(f);
        int before = __popcll(m & ((1ull << lane) - 1ull));
        if (lane == 0) wcnt[w] = __popcll(m);
        __syncthreads();
        int pre = 0, total = 0;
        #pragma unroll
        for (int j = 0; j < 8; ++j) {
            int x = wcnt[j];
            pre += (j < w) ? x : 0;
            total += x;
        }
        pcntC[c * NN + tid] = (unsigned char)(pre + before);  // coalesced row write
        unsigned* row = nbr + c * MAXD;
        int pos = pre + before;
        if (f && pos < MAXD) row[pos] = (unsigned)(tid << 7);
        int m2 = total < MAXD ? total : MAXD;
        for (int j = m2 + tid; j < MAXD; j += 512) row[j] = ZBYTE;
        __syncthreads();
    }

    const int tx = tid & 15, py = tid >> 4;   // 16 x 32 thread layout
    if (b < 256) {
        const int bi = b >> 4, bj = b & 15;
        float acc0 = 0.f, acc1 = 0.f;
        for (int kk = 0; kk < 256; kk += 32) {
            #pragma unroll
            for (int l = 0; l < 2; ++l) {
                int id = tid + (l << 9);
                int m = id >> 5, k = id & 31;
                As[k][m] = z[(bi * 32 + m) * 256 + kk + k];
                Bs[k][m] = z[(bj * 32 + m) * 256 + kk + k];
            }
            __syncthreads();
            #pragma unroll
            for (int k = 0; k < 32; ++k) {
                float a = As[k][py];
                float2 bb = *(const float2*)&Bs[k][tx * 2];
                acc0 = fmaf(a, bb.x, acc0);
                acc1 = fmaf(a, bb.y, acc1);
            }
            __syncthreads();
        }
        *(float2*)&out[(bi * 32 + py) * NN + bj * 32 + tx * 2] = make_float2(acc0, acc1);
    } else if (b < 272) {
        const int bi = b - 256;
        float (*As2)[34] = As;
        float (*Bs2)[68] = (float(*)[68])&Bs[0][0];
        float a0 = 0.f, a1 = 0.f, a2 = 0.f, a3 = 0.f;
        for (int kk = 0; kk < 256; kk += 16) {
            {
                int m = tid >> 4, k = tid & 15;
                As2[k][m] = z[(bi * 32 + m) * 256 + kk + k];
            }
            #pragma unroll
            for (int l = 0; l < 2; ++l) {
                int id = tid + (l << 9);
                int k = id >> 6, n2 = id & 63;
                Bs2[k][n2] = W1[(kk + k) * 64 + n2];
            }
            __syncthreads();
            #pragma unroll
            for (int k = 0; k < 16; ++k) {
                float a = As2[k][py];
                float4 bb = *(const float4*)&Bs2[k][tx * 4];
                a0 = fmaf(a, bb.x, a0);
                a1 = fmaf(a, bb.y, a1);
                a2 = fmaf(a, bb.z, a2);
                a3 = fmaf(a, bb.w, a3);
            }
            __syncthreads();
        }
        h4 v = {(_Float16)a0, (_Float16)a1, (_Float16)a2, (_Float16)a3};
        *(h4*)&g16[(bi * 32 + py) * NH + tx * 4] = v;
    }
}

// K2: visit-balanced hid. Grid (3, 512): block (c, b) handles i = 511-b,
// k in [c*i/3, (c+1)*i/3). g2[l][h] = deg_i[l]*g16[l][h] (rows >= i zeroed
// via deg=0): masking and sentinels free. Quarter q of each wave owns one k;
// 2-deep rolling list prefetch.
__global__ __launch_bounds__(1024, 8) void hidk(const unsigned* __restrict__ nbr,
                                                const unsigned char* __restrict__ pcntC,
                                                const _Float16* __restrict__ g16,
                                                const float* __restrict__ W2,
                                                float* __restrict__ hidt) {
    __shared__ _Float16 g2[NN * NH];   // 64 KB deg-scaled tile
    __shared__ float degl[NN];
    __shared__ unsigned char pcl[NN];
    const int i = 511 - (int)blockIdx.y;   // big i first
    const int c = (int)blockIdx.x;
    const int kc0 = (c * i) / 3, kc1 = ((c + 1) * i) / 3;
    if (kc0 >= kc1) return;
    const int tid = threadIdx.x, lane = tid & 63, w = tid >> 6;

    if (tid < NN) {
        int pc = (int)pcntC[tid * NN + i];           // per-block byte gather (L2-hot)
        pcl[tid] = (unsigned char)pc;
        degl[tid] = (tid < i) ? rsqrtf((float)(pc > 0 ? pc : 1)) : 0.0f;
    }
    __syncthreads();
    {
        const uint4* s = (const uint4*)g16;
        uint4* d = (uint4*)g2;
        #pragma unroll
        for (int u = 0; u < 4; ++u) {
            int t = tid + (u << 10);
            int l = t >> 3;
            uint4 raw = s[t];
            _Float16 dh = (_Float16)degl[l];
            h4 dv = {dh, dh, dh, dh};
            h4 a0 = ((h4*)&raw)[0] * dv;
            h4 a1 = ((h4*)&raw)[1] * dv;
            uint4 o;
            ((h4*)&o)[0] = a0; ((h4*)&o)[1] = a1;
            d[t] = o;
        }
    }
    __syncthreads();

    const int q = lane >> 4;                 // quarter 0..3
    const int lofs = (lane & 15) << 3;       // byte offset within 128B row
    const float4 w2v = *(const float4*)&W2[(lane & 15) << 2];
    const char* g2b = (const char*)g2;

    for (int k0 = kc0 + (w << 2); k0 < kc1; k0 += 64) {
        const int kq = k0 + q;
        const int kqc = kq < 511 ? kq : 511;
        int pk = (kq < kc1) ? (int)pcl[kqc] : 0;
        int mx = max(pk, __shfl_xor(pk, 16, 64));
        mx = max(mx, __shfl_xor(mx, 32, 64));
        const int nbu = __builtin_amdgcn_readfirstlane((mx + 3) >> 2);
        const uint4* l4 = (const uint4*)(nbr + kqc * MAXD);
        h4 acc0 = {}, acc1 = {};
        uint4 e0 = l4[0], e1 = l4[1];        // 2-deep rolling prefetch
        for (int g = 0; g < nbu; ++g) {
            uint4 en = l4[g + 2];            // harmless over-read (values never summed)
            acc0 += *(const h4*)(g2b + (e0.x + lofs));
            acc1 += *(const h4*)(g2b + (e0.y + lofs));
            acc0 += *(const h4*)(g2b + (e0.z + lofs));
            acc1 += *(const h4*)(g2b + (e0.w + lofs));
            e0 = e1; e1 = en;
        }
        h4 acc = acc0 + acc1;
        const float dk = degl[kqc];
        float val = fmaxf(dk * (float)acc[0], 0.f) * w2v.x
                  + fmaxf(dk * (float)acc[1], 0.f) * w2v.y
                  + fmaxf(dk * (float)acc[2], 0.f) * w2v.z
                  + fmaxf(dk * (float)acc[3], 0.f) * w2v.w;
        #pragma unroll
        for (int mm = 1; mm <= 8; mm <<= 1) val += __shfl_xor(val, mm, 64);
        if ((lane & 15) == 0 && kq < kc1) hidt[i * NN + kq] = val;
    }
}

// K3: supplement, quarter-owns-j. s[i][j] = 0.5*deg_j*sum_{k in nbr(j),k<i}
// deg_k*hid[i][k]; out[i][j] += s, out[j][i] += s. 16 lanes split the list
// (entries idx ql, ql+16, ...): sorted list => over-read entries have r >= i
// or sentinel -> phl[r] == 0 (branchless).
__global__ __launch_bounds__(512) void supp(const unsigned* __restrict__ nbr,
                                            const unsigned char* __restrict__ pcntC,
                                            const float* __restrict__ hidt,
                                            float* __restrict__ out) {
    __shared__ float phl[NN];
    __shared__ float degl[NN];
    __shared__ unsigned char pcl[NN];
    const int i = 511 - (int)blockIdx.x;
    if (i < 1) return;
    const int tid = threadIdx.x, lane = tid & 63, w = tid >> 6;
    const int q = lane >> 4, ql = lane & 15;

    {
        int pc = (int)pcntC[tid * NN + i];           // byte gather (L2-hot)
        float d = (tid < i) ? rsqrtf((float)(pc > 0 ? pc : 1)) : 0.0f;
        pcl[tid] = (unsigned char)pc;
        degl[tid] = d;
        phl[tid] = (tid < i) ? d * hidt[i * NN + tid] : 0.0f;
    }
    __syncthreads();

    for (int j0 = (w << 2); j0 < i; j0 += 32) {      // 8 waves x 4 quarters
        const int j = j0 + q;
        const int jc = j < 511 ? j : 511;
        int pj = (j < i) ? (int)pcl[jc] : 0;
        int mx = max(pj, __shfl_xor(pj, 16, 64));
        mx = max(mx, __shfl_xor(mx, 32, 64));
        const int T = __builtin_amdgcn_readfirstlane((mx + 15) >> 4);
        const unsigned* lst = nbr + jc * MAXD;
        float s = 0.f;
        for (int t = 0; t < T; ++t) {                // T <= 6; ql+16*5 <= 95 in-row
            unsigned e = lst[ql + (t << 4)];
            s += phl[e >> 7];                        // 0 beyond pj (r>=i or sentinel)
        }
        s += __shfl_xor(s, 1, 64);
        s += __shfl_xor(s, 2, 64);
        s += __shfl_xor(s, 4, 64);
        s += __shfl_xor(s, 8, 64);
        if (ql == 0 && j < i) {
            float sj = 0.5f * degl[j] * s;
            out[i * NN + j] += sj;
            out[j * NN + i] += sj;
        }
    }
}

extern "C" void kernel_launch(void* const* d_in, const int* in_sizes, int n_in,
                              void* d_out, int out_size, void* d_ws, size_t ws_size,
                              hipStream_t stream) {
    const float* z   = (const float*)d_in[0];
    const float* adj = (const float*)d_in[1];
    const float* W1  = (const float*)d_in[2];
    const float* W2  = (const float*)d_in[3];
    float* out = (float*)d_out;

    char* wsp = (char*)d_ws;
    unsigned*       nbr   = (unsigned*)      (wsp + 0);
    _Float16*       g16   = (_Float16*)      (wsp + 196608);
    unsigned char*  pcntC = (unsigned char*) (wsp + 262144);
    float*          hidt  = (float*)         (wsp + 524288);

    build_gemms<<<NN, 512, 0, stream>>>(adj, z, W1, nbr, pcntC, g16, out);
    hidk<<<dim3(3, NN), 1024, 0, stream>>>(nbr, pcntC, g16, W2, hidt);
    supp<<<NN, 512, 0, stream>>>(nbr, pcntC, hidt, out);
}

// Round 13
// 49.190 us; speedup vs baseline: 3.7826x; 1.2824x over previous
//
#include <hip/hip_runtime.h>
#include <hip/hip_bf16.h>

#define NN 512
#define NH 64
#define MAXD 96            // list capacity (deg mean 32, sigma 5.5 -> +11 sigma)
#define ZBYTE (511 * 128)  // sentinel -> byte offset of row 511 (deg=0 zeroes it)

typedef _Float16 h4 __attribute__((ext_vector_type(4)));

// ---------------- ws layout (bytes) ----------------
// nbr   : NN*MAXD*4 = 196608  @ 0        entries = r*128 (byte row offset), sentinel ZBYTE
// g16   : NN*NH*2   = 65536   @ 196608   fp16 z@W1 tile (unscaled)
// pcntC : NN*NN     = 262144  @ 262144   u8 pcntC[c][t]  (coalesced write by block c)
// pcntT : NN*NN     = 262144  @ 524288   u8 pcntT[i][c]  (coalesced read by i-blocks)
// ph    : NN*NN*4   = 1048576 @ 786432   f32 ph[i][k] = deg_k*hid[i][k], valid k<i
// st    : NN*NN*4   = 1048576 @ 1835008  f32 half-supplement, zero for j>=i
// total = 2883584

// K1: 512 blocks x 512 thr. Block b builds the neighbor list + its own
// contiguous pcntC row for column c = b (adj symmetric). Blocks 0..255 also
// compute a 32x32 tile of out = z@z^T; blocks 256..271 a g16 slab.
__global__ __launch_bounds__(512) void build_gemms(const float* __restrict__ adj,
                                                   const float* __restrict__ z,
                                                   const float* __restrict__ W1,
                                                   unsigned* __restrict__ nbr,
                                                   unsigned char* __restrict__ pcntC,
                                                   _Float16* __restrict__ g16,
                                                   float* __restrict__ out) {
    __shared__ float As[32][34];
    __shared__ float Bs[32][34];
    __shared__ int wcnt[8];
    const int b = (int)blockIdx.x;
    const int tid = (int)threadIdx.x;
    const int lane = tid & 63, w = tid >> 6;

    {   // build lists + own pcntC row for column c = b
        const int c = b;
        bool f = (adj[c * NN + tid] != 0.0f);
        unsigned long long m = __ballot(f);
        int before = __popcll(m & ((1ull << lane) - 1ull));
        if (lane == 0) wcnt[w] = __popcll(m);
        __syncthreads();
        int pre = 0, total = 0;
        #pragma unroll
        for (int j = 0; j < 8; ++j) {
            int x = wcnt[j];
            pre += (j < w) ? x : 0;
            total += x;
        }
        pcntC[c * NN + tid] = (unsigned char)(pre + before);  // coalesced row write
        unsigned* row = nbr + c * MAXD;
        int pos = pre + before;
        if (f && pos < MAXD) row[pos] = (unsigned)(tid << 7);
        int m2 = total < MAXD ? total : MAXD;
        for (int j = m2 + tid; j < MAXD; j += 512) row[j] = ZBYTE;
        __syncthreads();
    }

    const int tx = tid & 15, py = tid >> 4;   // 16 x 32 thread layout
    if (b < 256) {
        const int bi = b >> 4, bj = b & 15;
        float acc0 = 0.f, acc1 = 0.f;
        for (int kk = 0; kk < 256; kk += 32) {
            #pragma unroll
            for (int l = 0; l < 2; ++l) {
                int id = tid + (l << 9);
                int m = id >> 5, k = id & 31;
                As[k][m] = z[(bi * 32 + m) * 256 + kk + k];
                Bs[k][m] = z[(bj * 32 + m) * 256 + kk + k];
            }
            __syncthreads();
            #pragma unroll
            for (int k = 0; k < 32; ++k) {
                float a = As[k][py];
                float2 bb = *(const float2*)&Bs[k][tx * 2];
                acc0 = fmaf(a, bb.x, acc0);
                acc1 = fmaf(a, bb.y, acc1);
            }
            __syncthreads();
        }
        *(float2*)&out[(bi * 32 + py) * NN + bj * 32 + tx * 2] = make_float2(acc0, acc1);
    } else if (b < 272) {
        const int bi = b - 256;
        float (*As2)[34] = As;
        float (*Bs2)[68] = (float(*)[68])&Bs[0][0];
        float a0 = 0.f, a1 = 0.f, a2 = 0.f, a3 = 0.f;
        for (int kk = 0; kk < 256; kk += 16) {
            {
                int m = tid >> 4, k = tid & 15;
                As2[k][m] = z[(bi * 32 + m) * 256 + kk + k];
            }
            #pragma unroll
            for (int l = 0; l < 2; ++l) {
                int id = tid + (l << 9);
                int k = id >> 6, n2 = id & 63;
                Bs2[k][n2] = W1[(kk + k) * 64 + n2];
            }
            __syncthreads();
            #pragma unroll
            for (int k = 0; k < 16; ++k) {
                float a = As2[k][py];
                float4 bb = *(const float4*)&Bs2[k][tx * 4];
                a0 = fmaf(a, bb.x, a0);
                a1 = fmaf(a, bb.y, a1);
                a2 = fmaf(a, bb.z, a2);
                a3 = fmaf(a, bb.w, a3);
            }
            __syncthreads();
        }
        h4 v = {(_Float16)a0, (_Float16)a1, (_Float16)a2, (_Float16)a3};
        *(h4*)&g16[(bi * 32 + py) * NH + tx * 4] = v;
    }
}

// K1b: byte transpose pcntT[t][c] = pcntC[c][t]. 64 blocks, 64x64 tiles,
// both sides coalesced 8B accesses through an LDS tile.
__global__ __launch_bounds__(512) void transp(const unsigned char* __restrict__ pcntC,
                                              unsigned char* __restrict__ pcntT) {
    __shared__ unsigned char til[64][72];
    const int bx = (int)blockIdx.x;
    const int br = bx >> 3, bc = bx & 7;     // output row band (t), col band (c)
    const int tid = (int)threadIdx.x;
    const int rr = tid >> 3, c8 = (tid & 7) << 3;
    unsigned long long v = *(const unsigned long long*)
        &pcntC[(bc * 64 + rr) * NN + br * 64 + c8];
    #pragma unroll
    for (int u = 0; u < 8; ++u) til[rr][c8 + u] = (unsigned char)(v >> (u * 8));
    __syncthreads();
    unsigned long long o = 0;
    #pragma unroll
    for (int u = 0; u < 8; ++u)
        o |= (unsigned long long)til[c8 + u][rr] << (u * 8);
    *(unsigned long long*)&pcntT[(br * 64 + rr) * NN + bc * 64 + c8] = o;
}

// K2: visit-balanced hid. Grid (3, 512): block (c, b) handles i = 511-b,
// k in [c*i/3, (c+1)*i/3). g2[l][h] = deg_i[l]*g16[l][h] (rows >= i zeroed
// via deg=0): masking and sentinels free. Quarter q of each wave owns one k;
// 2-deep rolling list prefetch. Stores ph[i][k] = deg_k * hid[i][k].
__global__ __launch_bounds__(1024, 8) void hidk(const unsigned* __restrict__ nbr,
                                                const unsigned char* __restrict__ pcntT,
                                                const _Float16* __restrict__ g16,
                                                const float* __restrict__ W2,
                                                float* __restrict__ ph) {
    __shared__ _Float16 g2[NN * NH];   // 64 KB deg-scaled tile
    __shared__ float degl[NN];
    __shared__ unsigned char pcl[NN];
    const int i = 511 - (int)blockIdx.y;   // big i first
    const int c = (int)blockIdx.x;
    const int kc0 = (c * i) / 3, kc1 = ((c + 1) * i) / 3;
    if (kc0 >= kc1) return;
    const int tid = threadIdx.x, lane = tid & 63, w = tid >> 6;

    if (tid < NN) {
        int pc = (int)pcntT[i * NN + tid];           // coalesced 512B row
        pcl[tid] = (unsigned char)pc;
        degl[tid] = (tid < i) ? rsqrtf((float)(pc > 0 ? pc : 1)) : 0.0f;
    }
    __syncthreads();
    {
        const uint4* s = (const uint4*)g16;
        uint4* d = (uint4*)g2;
        #pragma unroll
        for (int u = 0; u < 4; ++u) {
            int t = tid + (u << 10);
            int l = t >> 3;
            uint4 raw = s[t];
            _Float16 dh = (_Float16)degl[l];
            h4 dv = {dh, dh, dh, dh};
            h4 a0 = ((h4*)&raw)[0] * dv;
            h4 a1 = ((h4*)&raw)[1] * dv;
            uint4 o;
            ((h4*)&o)[0] = a0; ((h4*)&o)[1] = a1;
            d[t] = o;
        }
    }
    __syncthreads();

    const int q = lane >> 4;                 // quarter 0..3
    const int lofs = (lane & 15) << 3;       // byte offset within 128B row
    const float4 w2v = *(const float4*)&W2[(lane & 15) << 2];
    const char* g2b = (const char*)g2;

    for (int k0 = kc0 + (w << 2); k0 < kc1; k0 += 64) {
        const int kq = k0 + q;
        const int kqc = kq < 511 ? kq : 511;
        int pk = (kq < kc1) ? (int)pcl[kqc] : 0;
        int mx = max(pk, __shfl_xor(pk, 16, 64));
        mx = max(mx, __shfl_xor(mx, 32, 64));
        const int nbu = __builtin_amdgcn_readfirstlane((mx + 3) >> 2);
        const uint4* l4 = (const uint4*)(nbr + kqc * MAXD);
        h4 acc0 = {}, acc1 = {};
        uint4 e0 = l4[0], e1 = l4[1];        // 2-deep rolling prefetch
        for (int g = 0; g < nbu; ++g) {
            uint4 en = l4[g + 2];            // harmless in-row over-read
            acc0 += *(const h4*)(g2b + (e0.x + lofs));
            acc1 += *(const h4*)(g2b + (e0.y + lofs));
            acc0 += *(const h4*)(g2b + (e0.z + lofs));
            acc1 += *(const h4*)(g2b + (e0.w + lofs));
            e0 = e1; e1 = en;
        }
        h4 acc = acc0 + acc1;
        const float dk = degl[kqc];
        float val = fmaxf(dk * (float)acc[0], 0.f) * w2v.x
                  + fmaxf(dk * (float)acc[1], 0.f) * w2v.y
                  + fmaxf(dk * (float)acc[2], 0.f) * w2v.z
                  + fmaxf(dk * (float)acc[3], 0.f) * w2v.w;
        #pragma unroll
        for (int mm = 1; mm <= 8; mm <<= 1) val += __shfl_xor(val, mm, 64);
        if ((lane & 15) == 0 && kq < kc1) ph[i * NN + kq] = dk * val;  // deg_k*hid
    }
}

// K3: half-supplement, ROW STORE ONLY (no RMW, no column scatter).
// st[i][j] = 0.5*deg_j*sum_{k in nbr(j), k<i} ph[i][k] for j<i, else 0.
__global__ __launch_bounds__(512) void supp(const unsigned* __restrict__ nbr,
                                            const unsigned char* __restrict__ pcntT,
                                            const float* __restrict__ ph,
                                            float* __restrict__ st) {
    __shared__ float phl[NN];
    const int i = 511 - (int)blockIdx.x;
    const int tid = threadIdx.x;
    const int pc = (int)pcntT[i * NN + tid];         // coalesced row
    phl[tid] = (tid < i) ? ph[i * NN + tid] : 0.0f;  // ph already deg-scaled
    __syncthreads();
    float sj = 0.0f;
    if (tid < i) {
        const float d = rsqrtf((float)(pc > 0 ? pc : 1));
        const uint4* l4 = (const uint4*)(nbr + tid * MAXD);
        const int nb = (pc + 3) >> 2;
        float s = 0.f;
        for (int g = 0; g < nb; ++g) {
            uint4 qv = l4[g];   // over-read entries land on phl[r>=i] == 0
            s += phl[qv.x >> 7] + phl[qv.y >> 7] + phl[qv.z >> 7] + phl[qv.w >> 7];
        }
        sj = 0.5f * d * s;
    }
    st[i * NN + tid] = sj;      // coalesced plain store, full row coverage
}

// K4: out += st + st^T. 64 blocks, 64x64 tiles, transposed side via LDS.
__global__ __launch_bounds__(512) void symm(const float* __restrict__ st,
                                            float* __restrict__ out) {
    __shared__ float tB[64][65];
    const int bx = (int)blockIdx.x;
    const int bi = bx >> 3, bj = bx & 7;
    const int tid = (int)threadIdx.x;
    const int r = tid >> 3, c0 = (tid & 7) << 3;
    // stage B = st[bj-band][bi-band]
    float4 b0 = *(const float4*)&st[(bj * 64 + r) * NN + bi * 64 + c0];
    float4 b1 = *(const float4*)&st[(bj * 64 + r) * NN + bi * 64 + c0 + 4];
    *(float4*)&tB[r][c0] = b0;
    *(float4*)&tB[r][c0 + 4] = b1;
    __syncthreads();
    const int o = (bi * 64 + r) * NN + bj * 64 + c0;
    float4 a0 = *(const float4*)&st[o];
    float4 a1 = *(const float4*)&st[o + 4];
    float4 o0 = *(const float4*)&out[o];
    float4 o1 = *(const float4*)&out[o + 4];
    float va[8] = {a0.x, a0.y, a0.z, a0.w, a1.x, a1.y, a1.z, a1.w};
    float vo[8] = {o0.x, o0.y, o0.z, o0.w, o1.x, o1.y, o1.z, o1.w};
    #pragma unroll
    for (int u = 0; u < 8; ++u) vo[u] += va[u] + tB[c0 + u][r];
    *(float4*)&out[o]     = make_float4(vo[0], vo[1], vo[2], vo[3]);
    *(float4*)&out[o + 4] = make_float4(vo[4], vo[5], vo[6], vo[7]);
}

extern "C" void kernel_launch(void* const* d_in, const int* in_sizes, int n_in,
                              void* d_out, int out_size, void* d_ws, size_t ws_size,
                              hipStream_t stream) {
    const float* z   = (const float*)d_in[0];
    const float* adj = (const float*)d_in[1];
    const float* W1  = (const float*)d_in[2];
    const float* W2  = (const float*)d_in[3];
    float* out = (float*)d_out;

    char* wsp = (char*)d_ws;
    unsigned*       nbr   = (unsigned*)      (wsp + 0);
    _Float16*       g16   = (_Float16*)      (wsp + 196608);
    unsigned char*  pcntC = (unsigned char*) (wsp + 262144);
    unsigned char*  pcntT = (unsigned char*) (wsp + 524288);
    float*          ph    = (float*)         (wsp + 786432);
    float*          st    = (float*)         (wsp + 1835008);

    build_gemms<<<NN, 512, 0, stream>>>(adj, z, W1, nbr, pcntC, g16, out);
    transp<<<64, 512, 0, stream>>>(pcntC, pcntT);
    hidk<<<dim3(3, NN), 1024, 0, stream>>>(nbr, pcntT, g16, W2, ph);
    supp<<<NN, 512, 0, stream>>>(nbr, pcntT, ph, st);
    symm<<<64, 512, 0, stream>>>(st, out);
}